// Round 10
// baseline (151.637 us; speedup 1.0000x reference)
//
#include <hip/hip_runtime.h>
#include <hip/hip_fp16.h>
#include <math.h>

#define SP 32768            // 32*32*32 voxels
#define PW 38               // padded volume width (zero ring around 34^3 logical)
#define PW2 (PW*PW)         // 1444
#define PVOX (PW*PW*PW)     // 54872

typedef short bf16x8 __attribute__((ext_vector_type(8)));
typedef unsigned short u16x4 __attribute__((ext_vector_type(4)));
typedef float f32x4 __attribute__((ext_vector_type(4)));
typedef _Float16 f16x8 __attribute__((ext_vector_type(8)));
union U8 { bf16x8 s; f16x8 h; };

__device__ __forceinline__ unsigned short f2b(float f) {
    unsigned u = __float_as_uint(f);
    u = (u + 0x7FFFu + ((u >> 16) & 1u)) >> 16;   // RNE
    return (unsigned short)u;
}
__device__ __forceinline__ float b2f1(unsigned short s) {
    return __uint_as_float(((unsigned)s) << 16);
}
// block voxel tile = 2(d) x 2(h) x 4(w); tile grid = 16(d) x 16(h) x 8(w)
__device__ __forceinline__ int vox_of(int sb, int v) {
    int tw = sb & 7, th = (sb >> 3) & 15, td = sb >> 7;
    int vw = v & 3, vh = (v >> 2) & 1, vd = v >> 3;
    return (((td << 1) + vd) << 10) + (((th << 1) + vh) << 5) + (tw << 2) + vw;
}

// ====== K1: weight prep | dwconv | inproj (self-staged weights) | ring zero ======
__global__ void k_front(const float* __restrict__ x, const float* __restrict__ dw,
                        const float* __restrict__ off_w, const float* __restrict__ mask_w,
                        const float* __restrict__ off_b, const float* __restrict__ mask_b,
                        const float* __restrict__ inp_w, const float* __restrict__ inp_b,
                        const float* __restrict__ out_w,
                        unsigned short* __restrict__ WcatB, float* __restrict__ bcat,
                        unsigned short* __restrict__ outB,
                        unsigned short* __restrict__ xcb, float* __restrict__ partials,
                        unsigned short* __restrict__ xpad) {
    int bb = blockIdx.x, tid = threadIdx.x;
    if (bb < 72) {                               // ---- weight prep (j < 288) ----
        int idx = bb * 256 + tid;
        int j = idx >> 6, k = idx & 63;
        if (j < 224) {
            float v = 0.f;
            if (j < 162) v = off_w[k * 162 + j];
            else if (j < 216) v = mask_w[k * 54 + (j - 162)];
            WcatB[j * 64 + k] = f2b(v);
            if (k == 0) bcat[j] = (j < 162) ? off_b[j] : (j < 216 ? mask_b[j - 162] : 0.f);
        } else {
            outB[(j - 224) * 64 + k] = f2b(out_w[k * 64 + (j - 224)]);
        }
        return;
    }
    if (bb < 2120) {                             // ---- dwconv 3x3x3, 4 outputs/thread ----
        int b4 = bb - 72;
        int e4 = b4 * 256 + tid;                 // group of 4 voxels along w
        int c = e4 >> 13, s4 = (e4 & 8191) << 2;
        int d = s4 >> 10, h = (s4 >> 5) & 31, w0 = s4 & 31;   // w0 in {0,4,...,28}
        const float* xs = x + (size_t)c * SP;
        const float* wt = dw + c * 27;
        float a0 = 0.f, a1 = 0.f, a2 = 0.f, a3 = 0.f;
#pragma unroll
        for (int kd = 0; kd < 3; ++kd) {
            int zz = d + kd - 1; if ((unsigned)zz >= 32u) continue;
#pragma unroll
            for (int kh = 0; kh < 3; ++kh) {
                int yy = h + kh - 1; if ((unsigned)yy >= 32u) continue;
                const float* row = xs + (zz << 10) + (yy << 5) + w0;
                float4 L = *(const float4*)row;
                float xl = (w0 > 0) ? row[-1] : 0.f;
                float xr = (w0 < 28) ? row[4] : 0.f;
                const float* wr = wt + kd * 9 + kh * 3;
                float wm = wr[0], wc = wr[1], wp = wr[2];
                a0 = __builtin_fmaf(wm, xl,  __builtin_fmaf(wc, L.x, __builtin_fmaf(wp, L.y, a0)));
                a1 = __builtin_fmaf(wm, L.x, __builtin_fmaf(wc, L.y, __builtin_fmaf(wp, L.z, a1)));
                a2 = __builtin_fmaf(wm, L.y, __builtin_fmaf(wc, L.z, __builtin_fmaf(wp, L.w, a2)));
                a3 = __builtin_fmaf(wm, L.z, __builtin_fmaf(wc, L.w, __builtin_fmaf(wp, xr,  a3)));
            }
        }
        u16x4 o4; o4[0] = f2b(a0); o4[1] = f2b(a1); o4[2] = f2b(a2); o4[3] = f2b(a3);
        *(u16x4*)(xcb + (size_t)e4 * 4) = o4;
        float s1 = a0 + a1 + a2 + a3;
        float s2 = a0 * a0 + a1 * a1 + a2 * a2 + a3 * a3;
#pragma unroll
        for (int off = 32; off > 0; off >>= 1) {
            s1 += __shfl_xor(s1, off);
            s2 += __shfl_xor(s2, off);
        }
        __shared__ float ws[8];
        int wv = tid >> 6, lane = tid & 63;
        if (lane == 0) { ws[wv * 2] = s1; ws[wv * 2 + 1] = s2; }
        __syncthreads();
        if (tid == 0) {
            partials[b4 * 2 + 0] = ws[0] + ws[2] + ws[4] + ws[6];
            partials[b4 * 2 + 1] = ws[1] + ws[3] + ws[5] + ws[7];
        }
        return;
    }
    if (bb < 2632) {                             // ---- inproj: x transpose + W stage ----
        __shared__ unsigned short tileT[64][72];  // [voxel][channel] bf16
        __shared__ unsigned short tileB[64][72];  // [out_ch n][in_ch k] bf16
        int s0b = (bb - 2120) * 64;
        int row = tid >> 6, lane = tid & 63;
        for (int c = row; c < 64; c += 4)
            tileT[lane][c] = f2b(x[(size_t)c * SP + s0b + lane]);
        {   // weight B^T tile: thread t -> col n = t&63, rows k0..k0+15
            int n = tid & 63, k0 = (tid >> 6) * 16;
            u16x4 wb[4];
#pragma unroll
            for (int i = 0; i < 16; ++i)
                wb[i >> 2][i & 3] = f2b(inp_w[(size_t)(k0 + i) * 64 + n]);
#pragma unroll
            for (int q = 0; q < 4; ++q)
                *(u16x4*)(&tileB[n][k0 + q * 4]) = wb[q];
        }
        __syncthreads();
        int wv = row, quad = lane >> 4, col = lane & 15;
        int s0 = s0b + wv * 16;
        bf16x8 a0 = *(const bf16x8*)(&tileT[wv * 16 + col][quad * 8]);
        bf16x8 a1 = *(const bf16x8*)(&tileT[wv * 16 + col][32 + quad * 8]);
        int vp[4];
#pragma unroll
        for (int r = 0; r < 4; ++r) {
            int s = s0 + (quad << 2) + r;        // orig voxel (d,h,w) at 38-coord +2
            vp[r] = (((s >> 10) + 2) * PW + ((s >> 5) & 31) + 2) * PW + (s & 31) + 2;
        }
#pragma unroll
        for (int nt = 0; nt < 4; ++nt) {
            int n0 = nt * 16;
            bf16x8 b0 = *(const bf16x8*)(&tileB[n0 + col][quad * 8]);
            bf16x8 b1 = *(const bf16x8*)(&tileB[n0 + col][32 + quad * 8]);
            f32x4 c = {0.f, 0.f, 0.f, 0.f};
            c = __builtin_amdgcn_mfma_f32_16x16x32_bf16(a0, b0, c, 0, 0, 0);
            c = __builtin_amdgcn_mfma_f32_16x16x32_bf16(a1, b1, c, 0, 0, 0);
            float bq = inp_b[n0 + col];
#pragma unroll
            for (int r = 0; r < 4; ++r)
                xpad[(size_t)vp[r] * 64 + n0 + col] =
                    __half_as_ushort(__float2half(c[r] + bq));
        }
        return;
    }
    // ---- ring zero (fp16) ----
    int cblk = bb - 2632;
    int j = tid >> 4, c4 = tid & 15;
    u16x4 z = {0, 0, 0, 0};
#pragma unroll
    for (int k = 0; k < 4; ++k) {
        int v = cblk * 64 + k * 16 + j;
        if (v >= PVOX) break;
        int zz = v / PW2, r = v - zz * PW2, yy = r / PW, xx = r - yy * PW;
        if (zz < 2 || zz > 33 || yy < 2 || yy > 33 || xx < 2 || xx > 33)
            *(u16x4*)(xpad + (size_t)v * 64 + c4 * 4) = z;
    }
}

// ========= K2: sampling as C @ VOL via f16 MFMA =========
// Region 6(z)x6(y)x8(x) -> 288 rows; C[16 vox][288] f16 coefficients per group.
__global__ void __launch_bounds__(256, 2) k_main(const unsigned short* __restrict__ xcb,
                                                 const float* __restrict__ partials,
                                                 const float* __restrict__ gn_w,
                                                 const float* __restrict__ gn_b,
                                                 const unsigned short* __restrict__ xpad,
                                                 const unsigned short* __restrict__ WcatB,
                                                 const float* __restrict__ bcat,
                                                 const unsigned short* __restrict__ outB,
                                                 const float* __restrict__ out_b,
                                                 float* __restrict__ out) {
    __shared__ unsigned short offs_u[16 * 176];  // 5632 B: bf16 offsets (2 grp x 84)
    __shared__ float om_mask[16 * 56];           // 3584 B: f32 mask logits->weights
    __shared__ unsigned short smb[16 * 72];      // 2304 B: A-tile, then S-tile
    __shared__ unsigned short vol[288 * 68];     // 39168 B: region rows, 68-elem pitch
    __shared__ unsigned short Cl[16 * 296];      // 9472 B: f16 coefficient matrix
    __shared__ float gnw_s[64], gnb_s[64], ws[8];
    int tid = threadIdx.x, wv = tid >> 6, lane = tid & 63;
    int quad = lane >> 4, col = lane & 15;
    int sb = ((blockIdx.x & 7) << 8) | (blockIdx.x >> 3);
    int tw = sb & 7, th = (sb >> 3) & 15, td = sb >> 7;
    // ---- phase 0: stage region (2304 x 16B units; 9/thread) into 68-pitch rows ----
    {
        const char* xp = (const char*)xpad;
#pragma unroll
        for (int it = 0; it < 9; ++it) {
            int u = tid + it * 256;
            int rr = u >> 3, c0 = (u & 7) * 8;
            int dz = rr / 48, rem = rr - dz * 48, dy = rem >> 3, dx = rem & 7;
            int pv = ((2 * td + dz) * PW + (2 * th + dy)) * PW + 4 * tw + dx;
            uint4 t = *(const uint4*)(xp + ((size_t)pv << 7) + (c0 << 1));
            unsigned short* dst = &vol[rr * 68 + c0];
            ((uint2*)dst)[0] = make_uint2(t.x, t.y);
            ((uint2*)dst)[1] = make_uint2(t.z, t.w);
        }
    }
    // ---- phase 0b: GN stats partial + gn params ----
    {
        if (tid < 64) { gnw_s[tid] = gn_w[tid]; gnb_s[tid] = gn_b[tid]; }
        float a = 0.f, b = 0.f;
#pragma unroll
        for (int i = 0; i < 4; ++i) {
            float4 t = *(const float4*)(partials + 4 * (tid + i * 256));
            a += t.x + t.z;
            b += t.y + t.w;
        }
#pragma unroll
        for (int off = 32; off > 0; off >>= 1) {
            a += __shfl_xor(a, off);
            b += __shfl_xor(b, off);
        }
        if (lane == 0) { ws[wv * 2] = a; ws[wv * 2 + 1] = b; }
    }
    __syncthreads();                             // #A
    const float Minv = 1.f / 2097152.f;
    float mu = (ws[0] + ws[2] + ws[4] + ws[6]) * Minv;
    float var = (ws[1] + ws[3] + ws[5] + ws[7]) * Minv - mu * mu;
    float rsq = rsqrtf(var + 1e-5f);
    // ---- phase 0c: A-tile (GN+GELU) once into smb; zero C ----
    {
        int v = tid >> 4, c0 = (tid & 15) * 4;
        int sv = vox_of(sb, v);
        u16x4 av;
#pragma unroll
        for (int i = 0; i < 4; ++i) {
            int c = c0 + i;
            float vx = (b2f1(xcb[(size_t)c * SP + sv]) - mu) * rsq * gnw_s[c] + gnb_s[c];
            float t2 = 1.5957691216057308f * (vx + 0.044715f * vx * vx * vx);
            av[i] = f2b(vx / (1.f + __expf(-t2)));
        }
        *(u16x4*)(&smb[v * 72 + c0]) = av;
        u16x4 z = {0, 0, 0, 0};
#pragma unroll
        for (int i = 0; i < 5; ++i) {
            int idx = tid + i * 256;
            if (idx < 1184) *(u16x4*)(&Cl[idx * 4]) = z;
        }
    }
    __syncthreads();                             // #B
    // ---- phase 1: offset+mask GEMM (16x64)@(64x224) ----
    {
        bf16x8 a0 = *(const bf16x8*)(&smb[col * 72 + quad * 8]);
        bf16x8 a1 = *(const bf16x8*)(&smb[col * 72 + 32 + quad * 8]);
        for (int jt = wv; jt < 14; jt += 4) {
            int n0 = jt * 16;
            bf16x8 b0 = *(const bf16x8*)(WcatB + (n0 + col) * 64 + quad * 8);
            bf16x8 b1 = *(const bf16x8*)(WcatB + (n0 + col) * 64 + 32 + quad * 8);
            f32x4 c = {0.f, 0.f, 0.f, 0.f};
            c = __builtin_amdgcn_mfma_f32_16x16x32_bf16(a0, b0, c, 0, 0, 0);
            c = __builtin_amdgcn_mfma_f32_16x16x32_bf16(a1, b1, c, 0, 0, 0);
            float bb = bcat[n0 + col];
            int n = n0 + col;
            if (n < 162) {
                int slot = n + ((n >= 81) ? 3 : 0);
#pragma unroll
                for (int r = 0; r < 4; ++r)
                    offs_u[(quad * 4 + r) * 176 + slot] = f2b(c[r] + bb);
            } else if (n < 216) {
                int n2 = n - 162;
                int slot = n2 + ((n2 >= 27) ? 1 : 0);
#pragma unroll
                for (int r = 0; r < 4; ++r)
                    om_mask[(quad * 4 + r) * 56 + slot] = c[r] + bb;
            }
        }
    }
    __syncthreads();                             // #C
    // ---- phase 2: softmax (replicated per voxel-half) ----
    {
        int row = lane >> 2, sub = lane & 3;
        int vloc = (wv & 1) * 8 + (row >> 1), g = row & 1;
        float* m = &om_mask[vloc * 56 + g * 28];
        float mv[7];
        float mx = -1e30f;
#pragma unroll
        for (int i = 0; i < 7; ++i) {
            int p = sub * 7 + i;
            mv[i] = (p < 27) ? m[p] : -1e30f;
            mx = fmaxf(mx, mv[i]);
        }
        mx = fmaxf(mx, __shfl_xor(mx, 1));
        mx = fmaxf(mx, __shfl_xor(mx, 2));
        float e[7], sm = 0.f;
#pragma unroll
        for (int i = 0; i < 7; ++i) { e[i] = __expf(mv[i] - mx); sm += e[i]; }
        sm += __shfl_xor(sm, 1);
        sm += __shfl_xor(sm, 2);
        float inv = 1.f / sm;
#pragma unroll
        for (int i = 0; i < 7; ++i) {
            int p = sub * 7 + i;
            if (p < 27) m[p] = e[i] * inv;
        }
    }
    __syncthreads();                             // #D
    // ---- per-group: build C then MFMA S-tiles ----
#pragma unroll
    for (int g = 0; g < 2; ++g) {
        if (g == 1) {                            // re-zero C for group 1
            u16x4 z = {0, 0, 0, 0};
#pragma unroll
            for (int i = 0; i < 5; ++i) {
                int idx = tid + i * 256;
                if (idx < 1184) *(u16x4*)(&Cl[idx * 4]) = z;
            }
            __syncthreads();
        }
        if (tid < 128) {                         // C-build: thread = (voxel, corner oct)
            int v = tid >> 3, oct = tid & 7;
            const unsigned short* orow = &offs_u[v * 176 + g * 84];
            const float* mrow = &om_mask[v * 56 + g * 28];
            int vw = v & 3, vh = (v >> 2) & 1, vd = v >> 3;
            float xb = (float)(vw + 1), yb = (float)(vh + 1), zb = (float)(vd + 1);
            int coff = (oct & 1) + ((oct >> 1) & 1) * 8 + ((oct >> 2) & 1) * 48;
            bool bx = oct & 1, by = oct & 2, bz = oct & 4;
            unsigned short* crow = &Cl[v * 296];
#pragma unroll
            for (int p = 0; p < 27; ++p) {
                const int px = p % 3, py = (p / 3) % 3, pz = p / 9;
                float ox = b2f1(orow[p * 3 + 0]);
                float oy = b2f1(orow[p * 3 + 1]);
                float oz = b2f1(orow[p * 3 + 2]);
                float mk = mrow[p];
                float ix = __builtin_fmaf(0.25f, ox, xb + (float)px);
                float iy = __builtin_fmaf(0.5f, oy, yb + (float)py);
                float iz = __builtin_fmaf(0.5f, oz, zb + (float)pz);
                ix = fminf(fmaxf(ix, 0.f), 6.999f);
                iy = fminf(fmaxf(iy, 0.f), 4.999f);
                iz = fminf(fmaxf(iz, 0.f), 4.999f);
                float xf = floorf(ix), yf = floorf(iy), zf = floorf(iz);
                float fx = ix - xf, fy = iy - yf, fz = iz - zf;
                int rr = (int)__builtin_fmaf(zf, 48.f, __builtin_fmaf(yf, 8.f, xf));
                float wx = bx ? fx : 1.f - fx;
                float wy = by ? fy : 1.f - fy;
                float wz = bz ? fz : 1.f - fz;
                float w = wx * wy * wz * mk;
                int a = rr + coff;
                float old = __half2float(__ushort_as_half(crow[a]));
                crow[a] = __half_as_ushort(__float2half(old + w));
            }
        }
        __syncthreads();                         // C ready
        // MFMA S = C @ VOL for this group's two 16-ch tiles (waves g*2, g*2+1)
        if ((wv >> 1) == g) {
            int n0 = wv * 16;
            f32x4 acc = {0.f, 0.f, 0.f, 0.f};
#pragma unroll
            for (int kt = 0; kt < 9; ++kt) {
                U8 a, b;
                a.s = *(const bf16x8*)(&Cl[col * 296 + kt * 32 + quad * 8]);
                int vb = (kt * 32 + quad * 8) * 68 + n0 + col;
#pragma unroll
                for (int j = 0; j < 8; ++j) b.s[j] = (short)vol[vb + j * 68];
                acc = __builtin_amdgcn_mfma_f32_16x16x32_f16(a.h, b.h, acc, 0, 0, 0);
            }
#pragma unroll
            for (int r = 0; r < 4; ++r)
                smb[(quad * 4 + r) * 72 + n0 + col] = f2b(acc[r]);
        }
        __syncthreads();                         // S-tiles done; C reusable
    }
    // ---- phase 4: out projection (16x64)@(64x64); wave wv does col tile wv ----
    {
        bf16x8 oa0 = *(const bf16x8*)(&smb[col * 72 + quad * 8]);
        bf16x8 oa1 = *(const bf16x8*)(&smb[col * 72 + 32 + quad * 8]);
        int n0 = wv * 16;
        bf16x8 b0 = *(const bf16x8*)(outB + (n0 + col) * 64 + quad * 8);
        bf16x8 b1 = *(const bf16x8*)(outB + (n0 + col) * 64 + 32 + quad * 8);
        f32x4 c = {0.f, 0.f, 0.f, 0.f};
        c = __builtin_amdgcn_mfma_f32_16x16x32_bf16(oa0, b0, c, 0, 0, 0);
        c = __builtin_amdgcn_mfma_f32_16x16x32_bf16(oa1, b1, c, 0, 0, 0);
        float bb = out_b[n0 + col];
        int vr[4];
#pragma unroll
        for (int r = 0; r < 4; ++r) vr[r] = vox_of(sb, quad * 4 + r);
#pragma unroll
        for (int r = 0; r < 4; ++r)
            out[(size_t)vr[r] * 64 + n0 + col] = c[r] + bb;
    }
}

extern "C" void kernel_launch(void* const* d_in, const int* in_sizes, int n_in,
                              void* d_out, int out_size, void* d_ws, size_t ws_size,
                              hipStream_t stream) {
    const float* x      = (const float*)d_in[0];
    const float* dw_w   = (const float*)d_in[1];
    const float* gn_w   = (const float*)d_in[2];
    const float* gn_b   = (const float*)d_in[3];
    const float* inp_w  = (const float*)d_in[4];
    const float* inp_b  = (const float*)d_in[5];
    const float* off_w  = (const float*)d_in[6];
    const float* off_b  = (const float*)d_in[7];
    const float* mask_w = (const float*)d_in[8];
    const float* mask_b = (const float*)d_in[9];
    const float* out_w  = (const float*)d_in[10];
    const float* out_b  = (const float*)d_in[11];

    char* B = (char*)d_ws;
    float*          partials = (float*)(B + 256);                // 16 KB used
    unsigned short* xcb      = (unsigned short*)(B + 65792);     // 4 MB (bf16)
    unsigned short* xpad     = (unsigned short*)(B + 16843008);  // 7.02 MB (fp16)
    unsigned short* WcatB    = (unsigned short*)(B + 30890240);  // 28 KB
    float*          bcat     = (float*)(B + 30918912);           // 1 KB
    unsigned short* outB     = (unsigned short*)(B + 30928128);  // 8 KB
    float* out = (float*)d_out;

    k_front<<<72 + 2048 + 512 + 858, 256, 0, stream>>>(x, dw_w, off_w, mask_w, off_b, mask_b,
                                                       inp_w, inp_b, out_w, WcatB, bcat, outB,
                                                       xcb, partials, xpad);
    k_main<<<2048, 256, 0, stream>>>(xcb, partials, gn_w, gn_b, xpad,
                                     WcatB, bcat, outB, out_b, out);
}

// Round 11
// 145.214 us; speedup vs baseline: 1.0442x; 1.0442x over previous
//
#include <hip/hip_runtime.h>
#include <hip/hip_fp16.h>
#include <math.h>

#define SP 32768            // 32*32*32 voxels
#define PW 38               // padded volume width (zero ring around 34^3 logical)
#define PW2 (PW*PW)         // 1444
#define PVOX (PW*PW*PW)     // 54872
#define OMS 228             // om_s row stride (floats): 28-pt padded offs(2*84) + masks(2*28)

typedef short bf16x8 __attribute__((ext_vector_type(8)));
typedef unsigned short u16x4 __attribute__((ext_vector_type(4)));
typedef float f32x4 __attribute__((ext_vector_type(4)));

__device__ __forceinline__ unsigned short f2b(float f) {
    unsigned u = __float_as_uint(f);
    u = (u + 0x7FFFu + ((u >> 16) & 1u)) >> 16;   // RNE
    return (unsigned short)u;
}
__device__ __forceinline__ float b2f1(unsigned short s) {
    return __uint_as_float(((unsigned)s) << 16);
}
__device__ __forceinline__ __half2 h2(unsigned u) {
    return *reinterpret_cast<__half2*>(&u);
}
// block voxel tile = 2(d) x 2(h) x 4(w); tile grid = 16(d) x 16(h) x 8(w)
__device__ __forceinline__ int vox_of(int sb, int v) {
    int tw = sb & 7, th = (sb >> 3) & 15, td = sb >> 7;
    int vw = v & 3, vh = (v >> 2) & 1, vd = v >> 3;
    return (((td << 1) + vd) << 10) + (((th << 1) + vh) << 5) + (tw << 2) + vw;
}

// ====== K1: weight prep | dwconv | inproj (self-staged weights) | ring zero ======
__global__ void k_front(const float* __restrict__ x, const float* __restrict__ dw,
                        const float* __restrict__ off_w, const float* __restrict__ mask_w,
                        const float* __restrict__ off_b, const float* __restrict__ mask_b,
                        const float* __restrict__ inp_w, const float* __restrict__ inp_b,
                        const float* __restrict__ out_w,
                        unsigned short* __restrict__ WcatB, float* __restrict__ bcat,
                        unsigned short* __restrict__ outB,
                        unsigned short* __restrict__ xcb, float* __restrict__ partials,
                        unsigned short* __restrict__ xpad) {
    int bb = blockIdx.x, tid = threadIdx.x;
    if (bb < 72) {                               // ---- weight prep (j < 288) ----
        int idx = bb * 256 + tid;
        int j = idx >> 6, k = idx & 63;
        if (j < 224) {
            float v = 0.f;
            if (j < 162) v = off_w[k * 162 + j];
            else if (j < 216) v = mask_w[k * 54 + (j - 162)];
            WcatB[j * 64 + k] = f2b(v);
            if (k == 0) bcat[j] = (j < 162) ? off_b[j] : (j < 216 ? mask_b[j - 162] : 0.f);
        } else {
            outB[(j - 224) * 64 + k] = f2b(out_w[k * 64 + (j - 224)]);
        }
        return;
    }
    if (bb < 2120) {                             // ---- dwconv 3x3x3, 4 outputs/thread ----
        int b4 = bb - 72;
        int e4 = b4 * 256 + tid;                 // group of 4 voxels along w
        int c = e4 >> 13, s4 = (e4 & 8191) << 2;
        int d = s4 >> 10, h = (s4 >> 5) & 31, w0 = s4 & 31;   // w0 in {0,4,...,28}
        const float* xs = x + (size_t)c * SP;
        const float* wt = dw + c * 27;
        float a0 = 0.f, a1 = 0.f, a2 = 0.f, a3 = 0.f;
#pragma unroll
        for (int kd = 0; kd < 3; ++kd) {
            int zz = d + kd - 1; if ((unsigned)zz >= 32u) continue;
#pragma unroll
            for (int kh = 0; kh < 3; ++kh) {
                int yy = h + kh - 1; if ((unsigned)yy >= 32u) continue;
                const float* row = xs + (zz << 10) + (yy << 5) + w0;
                float4 L = *(const float4*)row;
                float xl = (w0 > 0) ? row[-1] : 0.f;
                float xr = (w0 < 28) ? row[4] : 0.f;
                const float* wr = wt + kd * 9 + kh * 3;
                float wm = wr[0], wc = wr[1], wp = wr[2];
                a0 = __builtin_fmaf(wm, xl,  __builtin_fmaf(wc, L.x, __builtin_fmaf(wp, L.y, a0)));
                a1 = __builtin_fmaf(wm, L.x, __builtin_fmaf(wc, L.y, __builtin_fmaf(wp, L.z, a1)));
                a2 = __builtin_fmaf(wm, L.y, __builtin_fmaf(wc, L.z, __builtin_fmaf(wp, L.w, a2)));
                a3 = __builtin_fmaf(wm, L.z, __builtin_fmaf(wc, L.w, __builtin_fmaf(wp, xr,  a3)));
            }
        }
        u16x4 o4; o4[0] = f2b(a0); o4[1] = f2b(a1); o4[2] = f2b(a2); o4[3] = f2b(a3);
        *(u16x4*)(xcb + (size_t)e4 * 4) = o4;
        float s1 = a0 + a1 + a2 + a3;
        float s2 = a0 * a0 + a1 * a1 + a2 * a2 + a3 * a3;
#pragma unroll
        for (int off = 32; off > 0; off >>= 1) {
            s1 += __shfl_xor(s1, off);
            s2 += __shfl_xor(s2, off);
        }
        __shared__ float ws[8];
        int wv = tid >> 6, lane = tid & 63;
        if (lane == 0) { ws[wv * 2] = s1; ws[wv * 2 + 1] = s2; }
        __syncthreads();
        if (tid == 0) {
            partials[b4 * 2 + 0] = ws[0] + ws[2] + ws[4] + ws[6];
            partials[b4 * 2 + 1] = ws[1] + ws[3] + ws[5] + ws[7];
        }
        return;
    }
    if (bb < 2632) {                             // ---- inproj: x transpose + W stage ----
        __shared__ unsigned short tileT[64][72];  // [voxel][channel] bf16
        __shared__ unsigned short tileB[64][72];  // [out_ch n][in_ch k] bf16
        int s0b = (bb - 2120) * 64;
        int row = tid >> 6, lane = tid & 63;
        for (int c = row; c < 64; c += 4)
            tileT[lane][c] = f2b(x[(size_t)c * SP + s0b + lane]);
        {   // weight B^T tile: thread t -> col n = t&63, rows k0..k0+15
            int n = tid & 63, k0 = (tid >> 6) * 16;
            u16x4 wb[4];
#pragma unroll
            for (int i = 0; i < 16; ++i)
                wb[i >> 2][i & 3] = f2b(inp_w[(size_t)(k0 + i) * 64 + n]);
#pragma unroll
            for (int q = 0; q < 4; ++q)
                *(u16x4*)(&tileB[n][k0 + q * 4]) = wb[q];
        }
        __syncthreads();
        int wv = row, quad = lane >> 4, col = lane & 15;
        int s0 = s0b + wv * 16;
        bf16x8 a0 = *(const bf16x8*)(&tileT[wv * 16 + col][quad * 8]);
        bf16x8 a1 = *(const bf16x8*)(&tileT[wv * 16 + col][32 + quad * 8]);
        int vp[4];
#pragma unroll
        for (int r = 0; r < 4; ++r) {
            int s = s0 + (quad << 2) + r;        // orig voxel (d,h,w) at 38-coord +2
            vp[r] = (((s >> 10) + 2) * PW + ((s >> 5) & 31) + 2) * PW + (s & 31) + 2;
        }
#pragma unroll
        for (int nt = 0; nt < 4; ++nt) {
            int n0 = nt * 16;
            bf16x8 b0 = *(const bf16x8*)(&tileB[n0 + col][quad * 8]);
            bf16x8 b1 = *(const bf16x8*)(&tileB[n0 + col][32 + quad * 8]);
            f32x4 c = {0.f, 0.f, 0.f, 0.f};
            c = __builtin_amdgcn_mfma_f32_16x16x32_bf16(a0, b0, c, 0, 0, 0);
            c = __builtin_amdgcn_mfma_f32_16x16x32_bf16(a1, b1, c, 0, 0, 0);
            float bq = inp_b[n0 + col];
#pragma unroll
            for (int r = 0; r < 4; ++r)
                xpad[(size_t)vp[r] * 64 + n0 + col] =
                    __half_as_ushort(__float2half(c[r] + bq));
        }
        return;
    }
    // ---- ring zero (fp16) ----
    int cblk = bb - 2632;
    int j = tid >> 4, c4 = tid & 15;
    u16x4 z = {0, 0, 0, 0};
#pragma unroll
    for (int k = 0; k < 4; ++k) {
        int v = cblk * 64 + k * 16 + j;
        if (v >= PVOX) break;
        int zz = v / PW2, r = v - zz * PW2, yy = r / PW, xx = r - yy * PW;
        if (zz < 2 || zz > 33 || yy < 2 || yy > 33 || xx < 2 || xx > 33)
            *(u16x4*)(xpad + (size_t)v * 64 + c4 * 4) = z;
    }
}

// ---- VMEM sampler (proven round-4 path); global coords, clamp [0,36] ----
template<int P0, int NP>
__device__ __forceinline__ void sampleN(const float* __restrict__ orow,
                                        const float* __restrict__ mrow,
                                        const char* __restrict__ volc,
                                        float xb, float yb, float zb,
                                        float* __restrict__ acc) {
#pragma unroll
    for (int i = 0; i < NP; ++i) {
        const int p = P0 + i;
        const int px = p % 3, py = (p / 3) % 3, pz = p / 9;
        float ox = orow[p * 3 + 0], oy = orow[p * 3 + 1], oz = orow[p * 3 + 2];
        float mk = mrow[p];
        float ix = __builtin_fmaf(0.25f, ox, xb + (float)px);
        float iy = __builtin_fmaf(0.5f, oy, yb + (float)py);
        float iz = __builtin_fmaf(0.5f, oz, zb + (float)pz);
        ix = fminf(fmaxf(ix, 0.f), 36.f);
        iy = fminf(fmaxf(iy, 0.f), 36.f);
        iz = fminf(fmaxf(iz, 0.f), 36.f);
        float xf = floorf(ix), yf = floorf(iy), zf = floorf(iz);
        float fx = ix - xf, fy = iy - yf, fz = iz - zf;
        float fi = __builtin_fmaf(zf, (float)PW2, __builtin_fmaf(yf, (float)PW, xf));
        int ib = ((int)fi) << 7;                 // 128 B per voxel row (fp16)
        const char* base = volc + ib;
        uint4 r000 = *(const uint4*)(base);
        uint4 r001 = *(const uint4*)(base + 128);
        uint4 r010 = *(const uint4*)(base + PW * 128);
        uint4 r011 = *(const uint4*)(base + PW * 128 + 128);
        uint4 r100 = *(const uint4*)(base + PW2 * 128);
        uint4 r101 = *(const uint4*)(base + PW2 * 128 + 128);
        uint4 r110 = *(const uint4*)(base + (PW2 + PW) * 128);
        uint4 r111 = *(const uint4*)(base + (PW2 + PW) * 128 + 128);
        __half2 fx2 = __float2half2_rn(fx);
        __half2 fy2 = __float2half2_rn(fy);
        __half2 fz2 = __float2half2_rn(fz);
        #define TRI(comp, ci)                                                   \
        {                                                                       \
            __half2 t0 = __hfma2(fx2, __hsub2(h2(r001.comp), h2(r000.comp)), h2(r000.comp)); \
            __half2 t1 = __hfma2(fx2, __hsub2(h2(r011.comp), h2(r010.comp)), h2(r010.comp)); \
            __half2 t2 = __hfma2(fx2, __hsub2(h2(r101.comp), h2(r100.comp)), h2(r100.comp)); \
            __half2 t3 = __hfma2(fx2, __hsub2(h2(r111.comp), h2(r110.comp)), h2(r110.comp)); \
            __half2 u0 = __hfma2(fy2, __hsub2(t1, t0), t0);                     \
            __half2 u1 = __hfma2(fy2, __hsub2(t3, t2), t2);                     \
            __half2 rr = __hfma2(fz2, __hsub2(u1, u0), u0);                     \
            float2 ff = __half22float2(rr);                                     \
            acc[2 * ci + 0] = __builtin_fmaf(mk, ff.x, acc[2 * ci + 0]);        \
            acc[2 * ci + 1] = __builtin_fmaf(mk, ff.y, acc[2 * ci + 1]);        \
        }
        TRI(x, 0) TRI(y, 1) TRI(z, 2) TRI(w, 3)
        #undef TRI
    }
}

// ---- LDS sampler: region 6(z)x6(y)x8(x) rows (rr = 48z+8y+x); om preloaded ----
template<int P0, int NP>
__device__ __forceinline__ void sampleL(const float* __restrict__ orow,
                                        const float* __restrict__ mrow,
                                        const char* __restrict__ volp,
                                        float xb, float yb, float zb,
                                        float* __restrict__ acc) {
    float ox[NP], oy[NP], oz[NP], mk[NP];
#pragma unroll
    for (int i = 0; i < NP; ++i) {
        ox[i] = orow[(P0 + i) * 3 + 0];
        oy[i] = orow[(P0 + i) * 3 + 1];
        oz[i] = orow[(P0 + i) * 3 + 2];
        mk[i] = mrow[P0 + i];
    }
#pragma unroll
    for (int i = 0; i < NP; ++i) {
        const int p = P0 + i;
        const int px = p % 3, py = (p / 3) % 3, pz = p / 9;
        float ix = __builtin_fmaf(0.25f, ox[i], xb + (float)px);
        float iy = __builtin_fmaf(0.5f, oy[i], yb + (float)py);
        float iz = __builtin_fmaf(0.5f, oz[i], zb + (float)pz);
        // clamp to region (1-voxel margin; equals global clamp for |off|<1)
        ix = fminf(fmaxf(ix, 0.f), 6.999f);
        iy = fminf(fmaxf(iy, 0.f), 4.999f);
        iz = fminf(fmaxf(iz, 0.f), 4.999f);
        float xf = floorf(ix), yf = floorf(iy), zf = floorf(iz);
        float fx = ix - xf, fy = iy - yf, fz = iz - zf;
        float fi = __builtin_fmaf(zf, 48.f, __builtin_fmaf(yf, 8.f, xf));
        int rr = (int)fi;
        #define RD(o) (*(const uint4*)(volp + ((rr + (o)) << 7)))
        uint4 r000 = RD(0);
        uint4 r001 = RD(1);
        uint4 r010 = RD(8);
        uint4 r011 = RD(9);
        uint4 r100 = RD(48);
        uint4 r101 = RD(49);
        uint4 r110 = RD(56);
        uint4 r111 = RD(57);
        #undef RD
        __half2 fx2 = __float2half2_rn(fx);
        __half2 fy2 = __float2half2_rn(fy);
        __half2 fz2 = __float2half2_rn(fz);
        float m = mk[i];
        #define TRI(comp, ci)                                                   \
        {                                                                       \
            __half2 t0 = __hfma2(fx2, __hsub2(h2(r001.comp), h2(r000.comp)), h2(r000.comp)); \
            __half2 t1 = __hfma2(fx2, __hsub2(h2(r011.comp), h2(r010.comp)), h2(r010.comp)); \
            __half2 t2 = __hfma2(fx2, __hsub2(h2(r101.comp), h2(r100.comp)), h2(r100.comp)); \
            __half2 t3 = __hfma2(fx2, __hsub2(h2(r111.comp), h2(r110.comp)), h2(r110.comp)); \
            __half2 u0 = __hfma2(fy2, __hsub2(t1, t0), t0);                     \
            __half2 u1 = __hfma2(fy2, __hsub2(t3, t2), t2);                     \
            __half2 rr2 = __hfma2(fz2, __hsub2(u1, u0), u0);                    \
            float2 ff = __half22float2(rr2);                                    \
            acc[2 * ci + 0] = __builtin_fmaf(m, ff.x, acc[2 * ci + 0]);         \
            acc[2 * ci + 1] = __builtin_fmaf(m, ff.y, acc[2 * ci + 1]);         \
        }
        TRI(x, 0) TRI(y, 1) TRI(z, 2) TRI(w, 3)
        #undef TRI
    }
}

// ========= K2: main — fused GN (A-tile once) + hybrid VMEM/LDS sampling =========
__global__ void __launch_bounds__(256, 2) k_main(const unsigned short* __restrict__ xcb,
                                                 const float* __restrict__ partials,
                                                 const float* __restrict__ gn_w,
                                                 const float* __restrict__ gn_b,
                                                 const unsigned short* __restrict__ xpad,
                                                 const unsigned short* __restrict__ WcatB,
                                                 const float* __restrict__ bcat,
                                                 const unsigned short* __restrict__ outB,
                                                 const float* __restrict__ out_b,
                                                 float* __restrict__ out) {
    __shared__ float om_s[16 * OMS];             // 14592 B
    __shared__ unsigned short smb[16 * 72];      // 2304 B: A-tile, then S-tile
    __shared__ char vol[288 * 128];              // 36864 B: 6x6x8 region rows
    __shared__ float pbuf[16 * 64];              // 4096 B: LDS-half partials
    __shared__ float gnw_s[64], gnb_s[64], ws[8];
    int tid = threadIdx.x, wv = tid >> 6, lane = tid & 63;
    int quad = lane >> 4, col = lane & 15;
    // XCD swizzle over tiles: blocks sharing (blk&7) land on one XCD
    int sb = ((blockIdx.x & 7) << 8) | (blockIdx.x >> 3);
    int tw = sb & 7, th = (sb >> 3) & 15, td = sb >> 7;
    // ---- phase 0: stage 6x6x8 region (2304 x 16B units; 9 per thread) ----
    {
        const char* xp = (const char*)xpad;
#pragma unroll
        for (int k = 0; k < 3; ++k) {
            uint4 t[3];
#pragma unroll
            for (int j = 0; j < 3; ++j) {
                int u = tid + (k * 3 + j) * 256;
                int rr = u >> 3, ch = u & 7;
                int dz = rr / 48, rem = rr - dz * 48, dy = rem >> 3, dx = rem & 7;
                int pv = ((2 * td + dz) * PW + (2 * th + dy)) * PW + 4 * tw + dx;
                t[j] = *(const uint4*)(xp + ((size_t)pv << 7) + (ch << 4));
            }
#pragma unroll
            for (int j = 0; j < 3; ++j) {
                int u = tid + (k * 3 + j) * 256;
                *(uint4*)(vol + (u << 4)) = t[j];   // u*16 == rr*128 + ch*16 (linear)
            }
        }
    }
    // ---- phase 0b: GN stats (2048 partial pairs) + gn params to LDS ----
    {
        if (tid < 64) { gnw_s[tid] = gn_w[tid]; gnb_s[tid] = gn_b[tid]; }
        float a = 0.f, b = 0.f;
#pragma unroll
        for (int i = 0; i < 4; ++i) {
            float4 t = *(const float4*)(partials + 4 * (tid + i * 256));
            a += t.x + t.z;
            b += t.y + t.w;
        }
#pragma unroll
        for (int off = 32; off > 0; off >>= 1) {
            a += __shfl_xor(a, off);
            b += __shfl_xor(b, off);
        }
        if (lane == 0) { ws[wv * 2] = a; ws[wv * 2 + 1] = b; }
    }
    __syncthreads();                             // #A: ws, gn LDS, vol staging
    const float Minv = 1.f / 2097152.f;
    float mu = (ws[0] + ws[2] + ws[4] + ws[6]) * Minv;
    float var = (ws[1] + ws[3] + ws[5] + ws[7]) * Minv - mu * mu;
    float rsq = rsqrtf(var + 1e-5f);
    // ---- phase 0c: A-tile (GN+GELU) built ONCE into smb (4 gathers/thread) ----
    {
        int v = tid >> 4, c0 = (tid & 15) * 4;
        int sv = vox_of(sb, v);
        u16x4 av;
#pragma unroll
        for (int i = 0; i < 4; ++i) {
            int c = c0 + i;
            float vx = (b2f1(xcb[(size_t)c * SP + sv]) - mu) * rsq * gnw_s[c] + gnb_s[c];
            float t2 = 1.5957691216057308f * (vx + 0.044715f * vx * vx * vx);
            av[i] = f2b(vx / (1.f + __expf(-t2)));
        }
        *(u16x4*)(&smb[v * 72 + c0]) = av;
    }
    __syncthreads();                             // #B: A-tile ready
    // ---- phase 1: offset+mask GEMM (16x64)@(64x224); A-fragments from LDS ----
    {
        bf16x8 a0 = *(const bf16x8*)(&smb[col * 72 + quad * 8]);
        bf16x8 a1 = *(const bf16x8*)(&smb[col * 72 + 32 + quad * 8]);
        for (int jt = wv; jt < 14; jt += 4) {
            int n0 = jt * 16;
            bf16x8 b0 = *(const bf16x8*)(WcatB + (n0 + col) * 64 + quad * 8);
            bf16x8 b1 = *(const bf16x8*)(WcatB + (n0 + col) * 64 + 32 + quad * 8);
            f32x4 c = {0.f, 0.f, 0.f, 0.f};
            c = __builtin_amdgcn_mfma_f32_16x16x32_bf16(a0, b0, c, 0, 0, 0);
            c = __builtin_amdgcn_mfma_f32_16x16x32_bf16(a1, b1, c, 0, 0, 0);
            float bb = bcat[n0 + col];
            // remap feature n -> padded 28-pt slot
            int n = n0 + col, slot;
            if (n < 162) slot = n + ((n >= 81) ? 3 : 0);
            else { int n2 = n - 162; slot = 168 + n2 + ((n2 >= 27) ? 1 : 0); }
            if (n < 216) {
#pragma unroll
                for (int r = 0; r < 4; ++r)
                    om_s[(quad * 4 + r) * OMS + slot] = c[r] + bb;
            }
        }
    }
    __syncthreads();                             // #C: om_s ready
    // ---- phase 2: softmax, replicated per voxel-half; in-wave consumption ----
    {
        int row = lane >> 2, sub = lane & 3;     // 16 rows/wave, 4 lanes/row, 7 pts/lane
        int vloc = (wv & 1) * 8 + (row >> 1), g = row & 1;
        float* m = &om_s[vloc * OMS + 168 + g * 28];
        float mv[7];
        float mx = -1e30f;
#pragma unroll
        for (int i = 0; i < 7; ++i) {
            int p = sub * 7 + i;
            mv[i] = (p < 27) ? m[p] : -1e30f;
            mx = fmaxf(mx, mv[i]);
        }
        mx = fmaxf(mx, __shfl_xor(mx, 1));
        mx = fmaxf(mx, __shfl_xor(mx, 2));
        float e[7], sm = 0.f;
#pragma unroll
        for (int i = 0; i < 7; ++i) { e[i] = __expf(mv[i] - mx); sm += e[i]; }
        sm += __shfl_xor(sm, 1);
        sm += __shfl_xor(sm, 2);
        float inv = 1.f / sm;
#pragma unroll
        for (int i = 0; i < 7; ++i) {
            int p = sub * 7 + i;
            if (p < 27) m[p] = e[i] * inv;
        }
    }
    // ---- phase 3: wave-specialized sampling (VMEM pts 0-8 | LDS pts 9-26) ----
    {
        int half = wv & 1, mode = wv >> 1;
        int v = half * 8 + (lane >> 3);          // local voxel 0..15
        int oct = lane & 7, gg = oct >> 2;       // channels oct*8..oct*8+7
        const float* orow = &om_s[v * OMS + gg * 84];
        const float* mrow = &om_s[v * OMS + 168 + gg * 28];
        float acc[8] = {0.f, 0.f, 0.f, 0.f, 0.f, 0.f, 0.f, 0.f};
        if (mode == 0) {
            int sv = vox_of(sb, v);
            float zb = (float)((sv >> 10) + 1);
            float yb = (float)(((sv >> 5) & 31) + 1);
            float xb = (float)((sv & 31) + 1);
            sampleN<0, 9>(orow, mrow, (const char*)xpad + oct * 16, xb, yb, zb, acc);
        } else {
            int vw = v & 3, vh = (v >> 2) & 1, vd = v >> 3;
            sampleL<9, 18>(orow, mrow, vol + oct * 16,
                           (float)(vw + 1), (float)(vh + 1), (float)(vd + 1), acc);
            float* pp = &pbuf[v * 64 + oct * 8];
            *(f32x4*)(pp) = *(f32x4*)(acc);
            *(f32x4*)(pp + 4) = *(f32x4*)(acc + 4);
        }
        __syncthreads();                         // #D: pbuf ready (A-tile in smb now dead)
        if (mode == 0) {                         // combine halves + pack bf16
            const float* pp = &pbuf[v * 64 + oct * 8];
            bf16x8 sb8;
#pragma unroll
            for (int k = 0; k < 8; ++k) sb8[k] = (short)f2b(acc[k] + pp[k]);
            *(bf16x8*)(smb + v * 72 + oct * 8) = sb8;
        }
    }
    __syncthreads();                             // #E: smb (S-tile) ready
    // ---- phase 4: out projection (16x64)@(64x64); wave wv does col tile wv ----
    {
        bf16x8 oa0 = *(const bf16x8*)(smb + col * 72 + quad * 8);
        bf16x8 oa1 = *(const bf16x8*)(smb + col * 72 + 32 + quad * 8);
        int n0 = wv * 16;
        bf16x8 b0 = *(const bf16x8*)(outB + (n0 + col) * 64 + quad * 8);
        bf16x8 b1 = *(const bf16x8*)(outB + (n0 + col) * 64 + 32 + quad * 8);
        f32x4 c = {0.f, 0.f, 0.f, 0.f};
        c = __builtin_amdgcn_mfma_f32_16x16x32_bf16(oa0, b0, c, 0, 0, 0);
        c = __builtin_amdgcn_mfma_f32_16x16x32_bf16(oa1, b1, c, 0, 0, 0);
        float bb = out_b[n0 + col];
        int vr[4];
#pragma unroll
        for (int r = 0; r < 4; ++r) vr[r] = vox_of(sb, quad * 4 + r);
#pragma unroll
        for (int r = 0; r < 4; ++r)
            out[(size_t)vr[r] * 64 + n0 + col] = c[r] + bb;
    }
}

extern "C" void kernel_launch(void* const* d_in, const int* in_sizes, int n_in,
                              void* d_out, int out_size, void* d_ws, size_t ws_size,
                              hipStream_t stream) {
    const float* x      = (const float*)d_in[0];
    const float* dw_w   = (const float*)d_in[1];
    const float* gn_w   = (const float*)d_in[2];
    const float* gn_b   = (const float*)d_in[3];
    const float* inp_w  = (const float*)d_in[4];
    const float* inp_b  = (const float*)d_in[5];
    const float* off_w  = (const float*)d_in[6];
    const float* off_b  = (const float*)d_in[7];
    const float* mask_w = (const float*)d_in[8];
    const float* mask_b = (const float*)d_in[9];
    const float* out_w  = (const float*)d_in[10];
    const float* out_b  = (const float*)d_in[11];

    char* B = (char*)d_ws;
    float*          partials = (float*)(B + 256);                // 16 KB used
    unsigned short* xcb      = (unsigned short*)(B + 65792);     // 4 MB (bf16)
    unsigned short* xpad     = (unsigned short*)(B + 16843008);  // 7.02 MB (fp16)
    unsigned short* WcatB    = (unsigned short*)(B + 30890240);  // 28 KB
    float*          bcat     = (float*)(B + 30918912);           // 1 KB
    unsigned short* outB     = (unsigned short*)(B + 30928128);  // 8 KB
    float* out = (float*)d_out;

    k_front<<<72 + 2048 + 512 + 858, 256, 0, stream>>>(x, dw_w, off_w, mask_w, off_b, mask_b,
                                                       inp_w, inp_b, out_w, WcatB, bcat, outB,
                                                       xcb, partials, xpad);
    k_main<<<2048, 256, 0, stream>>>(xcb, partials, gn_w, gn_b, xpad,
                                     WcatB, bcat, outB, out_b, out);
}

// Round 14
// 144.371 us; speedup vs baseline: 1.0503x; 1.0058x over previous
//
#include <hip/hip_runtime.h>
#include <hip/hip_fp16.h>
#include <math.h>

#define SP 32768            // 32*32*32 voxels
#define PW 38               // padded volume width (zero ring around 34^3 logical)
#define PW2 (PW*PW)         // 1444
#define PVOX (PW*PW*PW)     // 54872
#define OMS 228             // om_s row stride (floats): 28-pt padded offs(2*84) + masks(2*28)

typedef short bf16x8 __attribute__((ext_vector_type(8)));
typedef unsigned short u16x4 __attribute__((ext_vector_type(4)));
typedef float f32x4 __attribute__((ext_vector_type(4)));

__device__ __forceinline__ unsigned short f2b(float f) {
    unsigned u = __float_as_uint(f);
    u = (u + 0x7FFFu + ((u >> 16) & 1u)) >> 16;   // RNE
    return (unsigned short)u;
}
__device__ __forceinline__ float b2f1(unsigned short s) {
    return __uint_as_float(((unsigned)s) << 16);
}
__device__ __forceinline__ __half2 h2(unsigned u) {
    return *reinterpret_cast<__half2*>(&u);
}
// block voxel tile = 2(d) x 2(h) x 4(w); tile grid = 16(d) x 16(h) x 8(w)
__device__ __forceinline__ int vox_of(int sb, int v) {
    int tw = sb & 7, th = (sb >> 3) & 15, td = sb >> 7;
    int vw = v & 3, vh = (v >> 2) & 1, vd = v >> 3;
    return (((td << 1) + vd) << 10) + (((th << 1) + vh) << 5) + (tw << 2) + vw;
}

// ====== K1: weight prep | dwconv | inproj (self-staged weights) | ring zero ======
__global__ void k_front(const float* __restrict__ x, const float* __restrict__ dw,
                        const float* __restrict__ off_w, const float* __restrict__ mask_w,
                        const float* __restrict__ off_b, const float* __restrict__ mask_b,
                        const float* __restrict__ inp_w, const float* __restrict__ inp_b,
                        const float* __restrict__ out_w,
                        unsigned short* __restrict__ WcatB, float* __restrict__ bcat,
                        unsigned short* __restrict__ outB,
                        unsigned short* __restrict__ xcb, float* __restrict__ partials,
                        unsigned short* __restrict__ xpad) {
    int bb = blockIdx.x, tid = threadIdx.x;
    if (bb < 72) {                               // ---- weight prep (j < 288) ----
        int idx = bb * 256 + tid;
        int j = idx >> 6, k = idx & 63;
        if (j < 224) {
            float v = 0.f;
            if (j < 162) v = off_w[k * 162 + j];
            else if (j < 216) v = mask_w[k * 54 + (j - 162)];
            WcatB[j * 64 + k] = f2b(v);
            if (k == 0) bcat[j] = (j < 162) ? off_b[j] : (j < 216 ? mask_b[j - 162] : 0.f);
        } else {
            outB[(j - 224) * 64 + k] = f2b(out_w[k * 64 + (j - 224)]);
        }
        return;
    }
    if (bb < 2120) {                             // ---- dwconv 3x3x3, 4 outputs/thread ----
        int b4 = bb - 72;
        int e4 = b4 * 256 + tid;                 // group of 4 voxels along w
        int c = e4 >> 13, s4 = (e4 & 8191) << 2;
        int d = s4 >> 10, h = (s4 >> 5) & 31, w0 = s4 & 31;   // w0 in {0,4,...,28}
        const float* xs = x + (size_t)c * SP;
        const float* wt = dw + c * 27;
        float a0 = 0.f, a1 = 0.f, a2 = 0.f, a3 = 0.f;
#pragma unroll
        for (int kd = 0; kd < 3; ++kd) {
            int zz = d + kd - 1; if ((unsigned)zz >= 32u) continue;
#pragma unroll
            for (int kh = 0; kh < 3; ++kh) {
                int yy = h + kh - 1; if ((unsigned)yy >= 32u) continue;
                const float* row = xs + (zz << 10) + (yy << 5) + w0;
                float4 L = *(const float4*)row;
                float xl = (w0 > 0) ? row[-1] : 0.f;
                float xr = (w0 < 28) ? row[4] : 0.f;
                const float* wr = wt + kd * 9 + kh * 3;
                float wm = wr[0], wc = wr[1], wp = wr[2];
                a0 = __builtin_fmaf(wm, xl,  __builtin_fmaf(wc, L.x, __builtin_fmaf(wp, L.y, a0)));
                a1 = __builtin_fmaf(wm, L.x, __builtin_fmaf(wc, L.y, __builtin_fmaf(wp, L.z, a1)));
                a2 = __builtin_fmaf(wm, L.y, __builtin_fmaf(wc, L.z, __builtin_fmaf(wp, L.w, a2)));
                a3 = __builtin_fmaf(wm, L.z, __builtin_fmaf(wc, L.w, __builtin_fmaf(wp, xr,  a3)));
            }
        }
        u16x4 o4; o4[0] = f2b(a0); o4[1] = f2b(a1); o4[2] = f2b(a2); o4[3] = f2b(a3);
        *(u16x4*)(xcb + (size_t)e4 * 4) = o4;
        float s1 = a0 + a1 + a2 + a3;
        float s2 = a0 * a0 + a1 * a1 + a2 * a2 + a3 * a3;
#pragma unroll
        for (int off = 32; off > 0; off >>= 1) {
            s1 += __shfl_xor(s1, off);
            s2 += __shfl_xor(s2, off);
        }
        __shared__ float ws[8];
        int wv = tid >> 6, lane = tid & 63;
        if (lane == 0) { ws[wv * 2] = s1; ws[wv * 2 + 1] = s2; }
        __syncthreads();
        if (tid == 0) {
            partials[b4 * 2 + 0] = ws[0] + ws[2] + ws[4] + ws[6];
            partials[b4 * 2 + 1] = ws[1] + ws[3] + ws[5] + ws[7];
        }
        return;
    }
    if (bb < 2632) {                             // ---- inproj: x transpose + W stage ----
        __shared__ unsigned short tileT[64][72];  // [voxel][channel] bf16
        __shared__ unsigned short tileB[64][72];  // [out_ch n][in_ch k] bf16
        int s0b = (bb - 2120) * 64;
        int row = tid >> 6, lane = tid & 63;
        for (int c = row; c < 64; c += 4)
            tileT[lane][c] = f2b(x[(size_t)c * SP + s0b + lane]);
        {   // weight B^T tile: thread t -> col n = t&63, rows k0..k0+15
            int n = tid & 63, k0 = (tid >> 6) * 16;
            u16x4 wb[4];
#pragma unroll
            for (int i = 0; i < 16; ++i)
                wb[i >> 2][i & 3] = f2b(inp_w[(size_t)(k0 + i) * 64 + n]);
#pragma unroll
            for (int q = 0; q < 4; ++q)
                *(u16x4*)(&tileB[n][k0 + q * 4]) = wb[q];
        }
        __syncthreads();
        int wv = row, quad = lane >> 4, col = lane & 15;
        int s0 = s0b + wv * 16;
        bf16x8 a0 = *(const bf16x8*)(&tileT[wv * 16 + col][quad * 8]);
        bf16x8 a1 = *(const bf16x8*)(&tileT[wv * 16 + col][32 + quad * 8]);
        int vp[4];
#pragma unroll
        for (int r = 0; r < 4; ++r) {
            int s = s0 + (quad << 2) + r;        // orig voxel (d,h,w) at 38-coord +2
            vp[r] = (((s >> 10) + 2) * PW + ((s >> 5) & 31) + 2) * PW + (s & 31) + 2;
        }
#pragma unroll
        for (int nt = 0; nt < 4; ++nt) {
            int n0 = nt * 16;
            bf16x8 b0 = *(const bf16x8*)(&tileB[n0 + col][quad * 8]);
            bf16x8 b1 = *(const bf16x8*)(&tileB[n0 + col][32 + quad * 8]);
            f32x4 c = {0.f, 0.f, 0.f, 0.f};
            c = __builtin_amdgcn_mfma_f32_16x16x32_bf16(a0, b0, c, 0, 0, 0);
            c = __builtin_amdgcn_mfma_f32_16x16x32_bf16(a1, b1, c, 0, 0, 0);
            float bq = inp_b[n0 + col];
#pragma unroll
            for (int r = 0; r < 4; ++r)
                xpad[(size_t)vp[r] * 64 + n0 + col] =
                    __half_as_ushort(__float2half(c[r] + bq));
        }
        return;
    }
    // ---- ring zero (fp16) ----
    int cblk = bb - 2632;
    int j = tid >> 4, c4 = tid & 15;
    u16x4 z = {0, 0, 0, 0};
#pragma unroll
    for (int k = 0; k < 4; ++k) {
        int v = cblk * 64 + k * 16 + j;
        if (v >= PVOX) break;
        int zz = v / PW2, r = v - zz * PW2, yy = r / PW, xx = r - yy * PW;
        if (zz < 2 || zz > 33 || yy < 2 || yy > 33 || xx < 2 || xx > 33)
            *(u16x4*)(xpad + (size_t)v * 64 + c4 * 4) = z;
    }
}

// ---- VMEM sampler (proven round-4 path); global coords, clamp [0,36] ----
template<int P0, int NP>
__device__ __forceinline__ void sampleN(const float* __restrict__ orow,
                                        const float* __restrict__ mrow,
                                        const char* __restrict__ volc,
                                        float xb, float yb, float zb,
                                        float* __restrict__ acc) {
#pragma unroll
    for (int i = 0; i < NP; ++i) {
        const int p = P0 + i;
        const int px = p % 3, py = (p / 3) % 3, pz = p / 9;
        float ox = orow[p * 3 + 0], oy = orow[p * 3 + 1], oz = orow[p * 3 + 2];
        float mk = mrow[p];
        float ix = __builtin_fmaf(0.25f, ox, xb + (float)px);
        float iy = __builtin_fmaf(0.5f, oy, yb + (float)py);
        float iz = __builtin_fmaf(0.5f, oz, zb + (float)pz);
        ix = fminf(fmaxf(ix, 0.f), 36.f);
        iy = fminf(fmaxf(iy, 0.f), 36.f);
        iz = fminf(fmaxf(iz, 0.f), 36.f);
        float xf = floorf(ix), yf = floorf(iy), zf = floorf(iz);
        float fx = ix - xf, fy = iy - yf, fz = iz - zf;
        float fi = __builtin_fmaf(zf, (float)PW2, __builtin_fmaf(yf, (float)PW, xf));
        int ib = ((int)fi) << 7;                 // 128 B per voxel row (fp16)
        const char* base = volc + ib;
        uint4 r000 = *(const uint4*)(base);
        uint4 r001 = *(const uint4*)(base + 128);
        uint4 r010 = *(const uint4*)(base + PW * 128);
        uint4 r011 = *(const uint4*)(base + PW * 128 + 128);
        uint4 r100 = *(const uint4*)(base + PW2 * 128);
        uint4 r101 = *(const uint4*)(base + PW2 * 128 + 128);
        uint4 r110 = *(const uint4*)(base + (PW2 + PW) * 128);
        uint4 r111 = *(const uint4*)(base + (PW2 + PW) * 128 + 128);
        __half2 fx2 = __float2half2_rn(fx);
        __half2 fy2 = __float2half2_rn(fy);
        __half2 fz2 = __float2half2_rn(fz);
        #define TRI(comp, ci)                                                   \
        {                                                                       \
            __half2 t0 = __hfma2(fx2, __hsub2(h2(r001.comp), h2(r000.comp)), h2(r000.comp)); \
            __half2 t1 = __hfma2(fx2, __hsub2(h2(r011.comp), h2(r010.comp)), h2(r010.comp)); \
            __half2 t2 = __hfma2(fx2, __hsub2(h2(r101.comp), h2(r100.comp)), h2(r100.comp)); \
            __half2 t3 = __hfma2(fx2, __hsub2(h2(r111.comp), h2(r110.comp)), h2(r110.comp)); \
            __half2 u0 = __hfma2(fy2, __hsub2(t1, t0), t0);                     \
            __half2 u1 = __hfma2(fy2, __hsub2(t3, t2), t2);                     \
            __half2 rr = __hfma2(fz2, __hsub2(u1, u0), u0);                     \
            float2 ff = __half22float2(rr);                                     \
            acc[2 * ci + 0] = __builtin_fmaf(mk, ff.x, acc[2 * ci + 0]);        \
            acc[2 * ci + 1] = __builtin_fmaf(mk, ff.y, acc[2 * ci + 1]);        \
        }
        TRI(x, 0) TRI(y, 1) TRI(z, 2) TRI(w, 3)
        #undef TRI
    }
}

// ========= K2: main — fused GN (A-tile once) + pure-VMEM point-split sampling =========
// Race-free softmax: 32 rows split disjointly across 4 waves, one writer per row.
__global__ void __launch_bounds__(256, 2) k_main(const unsigned short* __restrict__ xcb,
                                                 const float* __restrict__ partials,
                                                 const float* __restrict__ gn_w,
                                                 const float* __restrict__ gn_b,
                                                 const unsigned short* __restrict__ xpad,
                                                 const unsigned short* __restrict__ WcatB,
                                                 const float* __restrict__ bcat,
                                                 const unsigned short* __restrict__ outB,
                                                 const float* __restrict__ out_b,
                                                 float* __restrict__ out) {
    __shared__ float om_s[16 * OMS];             // 14592 B
    __shared__ unsigned short smb[16 * 72];      // 2304 B: A-tile, then S-tile
    __shared__ float pbuf[16 * 64];              // 4096 B: point-half-1 partials
    __shared__ float gnw_s[64], gnb_s[64], ws[8];
    int tid = threadIdx.x, wv = tid >> 6, lane = tid & 63;
    int quad = lane >> 4, col = lane & 15;
    // XCD swizzle over tiles: blocks sharing (blk&7) land on one XCD
    int sb = ((blockIdx.x & 7) << 8) | (blockIdx.x >> 3);
    // ---- phase 0: GN stats (2048 partial pairs) + gn params to LDS ----
    {
        if (tid < 64) { gnw_s[tid] = gn_w[tid]; gnb_s[tid] = gn_b[tid]; }
        float a = 0.f, b = 0.f;
#pragma unroll
        for (int i = 0; i < 4; ++i) {
            float4 t = *(const float4*)(partials + 4 * (tid + i * 256));
            a += t.x + t.z;
            b += t.y + t.w;
        }
#pragma unroll
        for (int off = 32; off > 0; off >>= 1) {
            a += __shfl_xor(a, off);
            b += __shfl_xor(b, off);
        }
        if (lane == 0) { ws[wv * 2] = a; ws[wv * 2 + 1] = b; }
    }
    __syncthreads();                             // #A
    const float Minv = 1.f / 2097152.f;
    float mu = (ws[0] + ws[2] + ws[4] + ws[6]) * Minv;
    float var = (ws[1] + ws[3] + ws[5] + ws[7]) * Minv - mu * mu;
    float rsq = rsqrtf(var + 1e-5f);
    // ---- phase 0c: A-tile (GN+GELU) built ONCE into smb (4 gathers/thread) ----
    {
        int v = tid >> 4, c0 = (tid & 15) * 4;
        int sv = vox_of(sb, v);
        u16x4 av;
#pragma unroll
        for (int i = 0; i < 4; ++i) {
            int c = c0 + i;
            float vx = (b2f1(xcb[(size_t)c * SP + sv]) - mu) * rsq * gnw_s[c] + gnb_s[c];
            float t2 = 1.5957691216057308f * (vx + 0.044715f * vx * vx * vx);
            av[i] = f2b(vx / (1.f + __expf(-t2)));
        }
        *(u16x4*)(&smb[v * 72 + c0]) = av;
    }
    __syncthreads();                             // #B: A-tile ready
    // ---- phase 1: offset+mask GEMM (16x64)@(64x224); A-fragments from LDS ----
    {
        bf16x8 a0 = *(const bf16x8*)(&smb[col * 72 + quad * 8]);
        bf16x8 a1 = *(const bf16x8*)(&smb[col * 72 + 32 + quad * 8]);
        for (int jt = wv; jt < 14; jt += 4) {
            int n0 = jt * 16;
            bf16x8 b0 = *(const bf16x8*)(WcatB + (n0 + col) * 64 + quad * 8);
            bf16x8 b1 = *(const bf16x8*)(WcatB + (n0 + col) * 64 + 32 + quad * 8);
            f32x4 c = {0.f, 0.f, 0.f, 0.f};
            c = __builtin_amdgcn_mfma_f32_16x16x32_bf16(a0, b0, c, 0, 0, 0);
            c = __builtin_amdgcn_mfma_f32_16x16x32_bf16(a1, b1, c, 0, 0, 0);
            float bb = bcat[n0 + col];
            // remap feature n -> padded 28-pt slot
            int n = n0 + col, slot;
            if (n < 162) slot = n + ((n >= 81) ? 3 : 0);
            else { int n2 = n - 162; slot = 168 + n2 + ((n2 >= 27) ? 1 : 0); }
            if (n < 216) {
#pragma unroll
                for (int r = 0; r < 4; ++r)
                    om_s[(quad * 4 + r) * OMS + slot] = c[r] + bb;
            }
        }
    }
    __syncthreads();                             // #C: om_s ready
    // ---- phase 2: softmax, 32 rows (16 vox x 2 grp), 8 rows/wave, ONE writer/row ----
    {
        int row = wv * 8 + (lane >> 3);          // 0..31, disjoint across waves
        int sub = lane & 7;                      // 8 lanes/row, 4 pts/lane
        int vloc = row >> 1, g = row & 1;
        float* m = &om_s[vloc * OMS + 168 + g * 28];
        float mv[4];
        float mx = -1e30f;
#pragma unroll
        for (int i = 0; i < 4; ++i) {
            int p = sub * 4 + i;
            mv[i] = (p < 27) ? m[p] : -1e30f;
            mx = fmaxf(mx, mv[i]);
        }
        mx = fmaxf(mx, __shfl_xor(mx, 1));
        mx = fmaxf(mx, __shfl_xor(mx, 2));
        mx = fmaxf(mx, __shfl_xor(mx, 4));
        float e[4], sm = 0.f;
#pragma unroll
        for (int i = 0; i < 4; ++i) { e[i] = __expf(mv[i] - mx); sm += e[i]; }
        sm += __shfl_xor(sm, 1);
        sm += __shfl_xor(sm, 2);
        sm += __shfl_xor(sm, 4);
        float inv = 1.f / sm;
#pragma unroll
        for (int i = 0; i < 4; ++i) {
            int p = sub * 4 + i;
            if (p < 27) m[p] = e[i] * inv;
        }
    }
    __syncthreads();                             // #C2: softmax visible to all waves
    // ---- phase 3: point-split VMEM sampling (waves 0-1: pts 0-13 | 2-3: pts 14-26) ----
    {
        int half = wv & 1, ph = wv >> 1;
        int v = half * 8 + (lane >> 3);          // local voxel 0..15
        int oct = lane & 7, gg = oct >> 2;       // channels oct*8..oct*8+7
        const float* orow = &om_s[v * OMS + gg * 84];
        const float* mrow = &om_s[v * OMS + 168 + gg * 28];
        int sv = vox_of(sb, v);
        float zb = (float)((sv >> 10) + 1);
        float yb = (float)(((sv >> 5) & 31) + 1);
        float xb = (float)((sv & 31) + 1);
        const char* volc = (const char*)xpad + oct * 16;
        float acc[8] = {0.f, 0.f, 0.f, 0.f, 0.f, 0.f, 0.f, 0.f};
        if (ph == 0) {
            sampleN<0, 14>(orow, mrow, volc, xb, yb, zb, acc);
        } else {
            sampleN<14, 13>(orow, mrow, volc, xb, yb, zb, acc);
            float* pp = &pbuf[v * 64 + oct * 8];
            *(f32x4*)(pp) = *(f32x4*)(acc);
            *(f32x4*)(pp + 4) = *(f32x4*)(acc + 4);
        }
        __syncthreads();                         // #D: pbuf ready (A-tile in smb now dead)
        if (ph == 0) {                           // combine halves + pack bf16
            const float* pp = &pbuf[v * 64 + oct * 8];
            bf16x8 sb8;
#pragma unroll
            for (int k = 0; k < 8; ++k) sb8[k] = (short)f2b(acc[k] + pp[k]);
            *(bf16x8*)(smb + v * 72 + oct * 8) = sb8;
        }
    }
    __syncthreads();                             // #E: smb (S-tile) ready
    // ---- phase 4: out projection (16x64)@(64x64); wave wv does col tile wv ----
    {
        bf16x8 oa0 = *(const bf16x8*)(smb + col * 72 + quad * 8);
        bf16x8 oa1 = *(const bf16x8*)(smb + col * 72 + 32 + quad * 8);
        int n0 = wv * 16;
        bf16x8 b0 = *(const bf16x8*)(outB + (n0 + col) * 64 + quad * 8);
        bf16x8 b1 = *(const bf16x8*)(outB + (n0 + col) * 64 + 32 + quad * 8);
        f32x4 c = {0.f, 0.f, 0.f, 0.f};
        c = __builtin_amdgcn_mfma_f32_16x16x32_bf16(oa0, b0, c, 0, 0, 0);
        c = __builtin_amdgcn_mfma_f32_16x16x32_bf16(oa1, b1, c, 0, 0, 0);
        float bb = out_b[n0 + col];
        int vr[4];
#pragma unroll
        for (int r = 0; r < 4; ++r) vr[r] = vox_of(sb, quad * 4 + r);
#pragma unroll
        for (int r = 0; r < 4; ++r)
            out[(size_t)vr[r] * 64 + n0 + col] = c[r] + bb;
    }
}

extern "C" void kernel_launch(void* const* d_in, const int* in_sizes, int n_in,
                              void* d_out, int out_size, void* d_ws, size_t ws_size,
                              hipStream_t stream) {
    const float* x      = (const float*)d_in[0];
    const float* dw_w   = (const float*)d_in[1];
    const float* gn_w   = (const float*)d_in[2];
    const float* gn_b   = (const float*)d_in[3];
    const float* inp_w  = (const float*)d_in[4];
    const float* inp_b  = (const float*)d_in[5];
    const float* off_w  = (const float*)d_in[6];
    const float* off_b  = (const float*)d_in[7];
    const float* mask_w = (const float*)d_in[8];
    const float* mask_b = (const float*)d_in[9];
    const float* out_w  = (const float*)d_in[10];
    const float* out_b  = (const float*)d_in[11];

    char* B = (char*)d_ws;
    float*          partials = (float*)(B + 256);                // 16 KB used
    unsigned short* xcb      = (unsigned short*)(B + 65792);     // 4 MB (bf16)
    unsigned short* xpad     = (unsigned short*)(B + 16843008);  // 7.02 MB (fp16)
    unsigned short* WcatB    = (unsigned short*)(B + 30890240);  // 28 KB
    float*          bcat     = (float*)(B + 30918912);           // 1 KB
    unsigned short* outB     = (unsigned short*)(B + 30928128);  // 8 KB
    float* out = (float*)d_out;

    k_front<<<72 + 2048 + 512 + 858, 256, 0, stream>>>(x, dw_w, off_w, mask_w, off_b, mask_b,
                                                       inp_w, inp_b, out_w, WcatB, bcat, outB,
                                                       xcb, partials, xpad);
    k_main<<<2048, 256, 0, stream>>>(xcb, partials, gn_w, gn_b, xpad,
                                     WcatB, bcat, outB, out_b, out);
}

// Round 15
// 139.378 us; speedup vs baseline: 1.0880x; 1.0358x over previous
//
#include <hip/hip_runtime.h>
#include <hip/hip_fp16.h>
#include <math.h>

#define SP 32768            // 32*32*32 voxels
#define PW 38               // padded volume width (zero ring around 34^3 logical)
#define PW2 (PW*PW)         // 1444
#define PVOX (PW*PW*PW)     // 54872
#define OMS 228             // om_s row stride (floats): 28-pt padded offs(2*84) + masks(2*28)

typedef short bf16x8 __attribute__((ext_vector_type(8)));
typedef unsigned short u16x4 __attribute__((ext_vector_type(4)));
typedef unsigned short u16x8 __attribute__((ext_vector_type(8)));
typedef float f32x4 __attribute__((ext_vector_type(4)));

__device__ __forceinline__ unsigned short f2b(float f) {
    unsigned u = __float_as_uint(f);
    u = (u + 0x7FFFu + ((u >> 16) & 1u)) >> 16;   // RNE
    return (unsigned short)u;
}
__device__ __forceinline__ float b2f1(unsigned short s) {
    return __uint_as_float(((unsigned)s) << 16);
}
__device__ __forceinline__ __half2 h2(unsigned u) {
    return *reinterpret_cast<__half2*>(&u);
}
// block voxel tile = 2(d) x 2(h) x 4(w); tile grid = 16(d) x 16(h) x 8(w)
__device__ __forceinline__ int vox_of(int sb, int v) {
    int tw = sb & 7, th = (sb >> 3) & 15, td = sb >> 7;
    int vw = v & 3, vh = (v >> 2) & 1, vd = v >> 3;
    return (((td << 1) + vd) << 10) + (((th << 1) + vh) << 5) + (tw << 2) + vw;
}

// ====== K1: weight prep | dwconv(x8) | inproj (self-staged weights) | ring zero ======
__global__ void k_front(const float* __restrict__ x, const float* __restrict__ dw,
                        const float* __restrict__ off_w, const float* __restrict__ mask_w,
                        const float* __restrict__ off_b, const float* __restrict__ mask_b,
                        const float* __restrict__ inp_w, const float* __restrict__ inp_b,
                        const float* __restrict__ out_w,
                        unsigned short* __restrict__ WcatB, float* __restrict__ bcat,
                        unsigned short* __restrict__ outB,
                        unsigned short* __restrict__ xcb, float* __restrict__ partials,
                        unsigned short* __restrict__ xpad) {
    int bb = blockIdx.x, tid = threadIdx.x;
    if (bb < 72) {                               // ---- weight prep (j < 288) ----
        int idx = bb * 256 + tid;
        int j = idx >> 6, k = idx & 63;
        if (j < 224) {
            float v = 0.f;
            if (j < 162) v = off_w[k * 162 + j];
            else if (j < 216) v = mask_w[k * 54 + (j - 162)];
            WcatB[j * 64 + k] = f2b(v);
            if (k == 0) bcat[j] = (j < 162) ? off_b[j] : (j < 216 ? mask_b[j - 162] : 0.f);
        } else {
            outB[(j - 224) * 64 + k] = f2b(out_w[k * 64 + (j - 224)]);
        }
        return;
    }
    if (bb < 1096) {                             // ---- dwconv 3x3x3, 8 outputs/thread ----
        int b8 = bb - 72;
        int e8 = b8 * 256 + tid;                 // group of 8 voxels along w
        int c = e8 >> 12, s8 = (e8 & 4095) << 3;
        int d = s8 >> 10, h = (s8 >> 5) & 31, w0 = s8 & 31;   // w0 in {0,8,16,24}
        const float* xs = x + (size_t)c * SP;
        const float* wt = dw + c * 27;
        float a0 = 0.f, a1 = 0.f, a2 = 0.f, a3 = 0.f;
        float a4 = 0.f, a5 = 0.f, a6 = 0.f, a7 = 0.f;
#pragma unroll
        for (int kd = 0; kd < 3; ++kd) {
            int zz = d + kd - 1; if ((unsigned)zz >= 32u) continue;
#pragma unroll
            for (int kh = 0; kh < 3; ++kh) {
                int yy = h + kh - 1; if ((unsigned)yy >= 32u) continue;
                const float* row = xs + (zz << 10) + (yy << 5) + w0;
                float4 L0 = *(const float4*)row;
                float4 L1 = *(const float4*)(row + 4);
                float xl = (w0 > 0) ? row[-1] : 0.f;
                float xr = (w0 < 24) ? row[8] : 0.f;
                const float* wr = wt + kd * 9 + kh * 3;
                float wm = wr[0], wc = wr[1], wp = wr[2];
                a0 = __builtin_fmaf(wm, xl,   __builtin_fmaf(wc, L0.x, __builtin_fmaf(wp, L0.y, a0)));
                a1 = __builtin_fmaf(wm, L0.x, __builtin_fmaf(wc, L0.y, __builtin_fmaf(wp, L0.z, a1)));
                a2 = __builtin_fmaf(wm, L0.y, __builtin_fmaf(wc, L0.z, __builtin_fmaf(wp, L0.w, a2)));
                a3 = __builtin_fmaf(wm, L0.z, __builtin_fmaf(wc, L0.w, __builtin_fmaf(wp, L1.x, a3)));
                a4 = __builtin_fmaf(wm, L0.w, __builtin_fmaf(wc, L1.x, __builtin_fmaf(wp, L1.y, a4)));
                a5 = __builtin_fmaf(wm, L1.x, __builtin_fmaf(wc, L1.y, __builtin_fmaf(wp, L1.z, a5)));
                a6 = __builtin_fmaf(wm, L1.y, __builtin_fmaf(wc, L1.z, __builtin_fmaf(wp, L1.w, a6)));
                a7 = __builtin_fmaf(wm, L1.z, __builtin_fmaf(wc, L1.w, __builtin_fmaf(wp, xr,  a7)));
            }
        }
        u16x8 o8;
        o8[0] = f2b(a0); o8[1] = f2b(a1); o8[2] = f2b(a2); o8[3] = f2b(a3);
        o8[4] = f2b(a4); o8[5] = f2b(a5); o8[6] = f2b(a6); o8[7] = f2b(a7);
        *(u16x8*)(xcb + (size_t)e8 * 8) = o8;
        float s1 = a0 + a1 + a2 + a3 + a4 + a5 + a6 + a7;
        float s2 = a0 * a0 + a1 * a1 + a2 * a2 + a3 * a3
                 + a4 * a4 + a5 * a5 + a6 * a6 + a7 * a7;
#pragma unroll
        for (int off = 32; off > 0; off >>= 1) {
            s1 += __shfl_xor(s1, off);
            s2 += __shfl_xor(s2, off);
        }
        __shared__ float ws[8];
        int wv = tid >> 6, lane = tid & 63;
        if (lane == 0) { ws[wv * 2] = s1; ws[wv * 2 + 1] = s2; }
        __syncthreads();
        if (tid == 0) {
            partials[b8 * 2 + 0] = ws[0] + ws[2] + ws[4] + ws[6];
            partials[b8 * 2 + 1] = ws[1] + ws[3] + ws[5] + ws[7];
        }
        return;
    }
    if (bb < 1608) {                             // ---- inproj: x transpose + W stage ----
        __shared__ unsigned short tileT[64][72];  // [voxel][channel] bf16
        __shared__ unsigned short tileB[64][72];  // [out_ch n][in_ch k] bf16
        int s0b = (bb - 1096) * 64;
        int row = tid >> 6, lane = tid & 63;
        for (int c = row; c < 64; c += 4)
            tileT[lane][c] = f2b(x[(size_t)c * SP + s0b + lane]);
        {   // weight B^T tile: thread t -> col n = t&63, rows k0..k0+15
            int n = tid & 63, k0 = (tid >> 6) * 16;
            u16x4 wb[4];
#pragma unroll
            for (int i = 0; i < 16; ++i)
                wb[i >> 2][i & 3] = f2b(inp_w[(size_t)(k0 + i) * 64 + n]);
#pragma unroll
            for (int q = 0; q < 4; ++q)
                *(u16x4*)(&tileB[n][k0 + q * 4]) = wb[q];
        }
        __syncthreads();
        int wv = row, quad = lane >> 4, col = lane & 15;
        int s0 = s0b + wv * 16;
        bf16x8 a0 = *(const bf16x8*)(&tileT[wv * 16 + col][quad * 8]);
        bf16x8 a1 = *(const bf16x8*)(&tileT[wv * 16 + col][32 + quad * 8]);
        int vp[4];
#pragma unroll
        for (int r = 0; r < 4; ++r) {
            int s = s0 + (quad << 2) + r;        // orig voxel (d,h,w) at 38-coord +2
            vp[r] = (((s >> 10) + 2) * PW + ((s >> 5) & 31) + 2) * PW + (s & 31) + 2;
        }
#pragma unroll
        for (int nt = 0; nt < 4; ++nt) {
            int n0 = nt * 16;
            bf16x8 b0 = *(const bf16x8*)(&tileB[n0 + col][quad * 8]);
            bf16x8 b1 = *(const bf16x8*)(&tileB[n0 + col][32 + quad * 8]);
            f32x4 c = {0.f, 0.f, 0.f, 0.f};
            c = __builtin_amdgcn_mfma_f32_16x16x32_bf16(a0, b0, c, 0, 0, 0);
            c = __builtin_amdgcn_mfma_f32_16x16x32_bf16(a1, b1, c, 0, 0, 0);
            float bq = inp_b[n0 + col];
#pragma unroll
            for (int r = 0; r < 4; ++r)
                xpad[(size_t)vp[r] * 64 + n0 + col] =
                    __half_as_ushort(__float2half(c[r] + bq));
        }
        return;
    }
    // ---- ring zero (fp16) ----
    int cblk = bb - 1608;
    int j = tid >> 4, c4 = tid & 15;
    u16x4 z = {0, 0, 0, 0};
#pragma unroll
    for (int k = 0; k < 4; ++k) {
        int v = cblk * 64 + k * 16 + j;
        if (v >= PVOX) break;
        int zz = v / PW2, r = v - zz * PW2, yy = r / PW, xx = r - yy * PW;
        if (zz < 2 || zz > 33 || yy < 2 || yy > 33 || xx < 2 || xx > 33)
            *(u16x4*)(xpad + (size_t)v * 64 + c4 * 4) = z;
    }
}

// ---- VMEM sampler (proven round-4 path); global coords, clamp [0,36] ----
template<int P0, int NP>
__device__ __forceinline__ void sampleN(const float* __restrict__ orow,
                                        const float* __restrict__ mrow,
                                        const char* __restrict__ volc,
                                        float xb, float yb, float zb,
                                        float* __restrict__ acc) {
#pragma unroll
    for (int i = 0; i < NP; ++i) {
        const int p = P0 + i;
        const int px = p % 3, py = (p / 3) % 3, pz = p / 9;
        float ox = orow[p * 3 + 0], oy = orow[p * 3 + 1], oz = orow[p * 3 + 2];
        float mk = mrow[p];
        float ix = __builtin_fmaf(0.25f, ox, xb + (float)px);
        float iy = __builtin_fmaf(0.5f, oy, yb + (float)py);
        float iz = __builtin_fmaf(0.5f, oz, zb + (float)pz);
        ix = fminf(fmaxf(ix, 0.f), 36.f);
        iy = fminf(fmaxf(iy, 0.f), 36.f);
        iz = fminf(fmaxf(iz, 0.f), 36.f);
        float xf = floorf(ix), yf = floorf(iy), zf = floorf(iz);
        float fx = ix - xf, fy = iy - yf, fz = iz - zf;
        float fi = __builtin_fmaf(zf, (float)PW2, __builtin_fmaf(yf, (float)PW, xf));
        int ib = ((int)fi) << 7;                 // 128 B per voxel row (fp16)
        const char* base = volc + ib;
        uint4 r000 = *(const uint4*)(base);
        uint4 r001 = *(const uint4*)(base + 128);
        uint4 r010 = *(const uint4*)(base + PW * 128);
        uint4 r011 = *(const uint4*)(base + PW * 128 + 128);
        uint4 r100 = *(const uint4*)(base + PW2 * 128);
        uint4 r101 = *(const uint4*)(base + PW2 * 128 + 128);
        uint4 r110 = *(const uint4*)(base + (PW2 + PW) * 128);
        uint4 r111 = *(const uint4*)(base + (PW2 + PW) * 128 + 128);
        __half2 fx2 = __float2half2_rn(fx);
        __half2 fy2 = __float2half2_rn(fy);
        __half2 fz2 = __float2half2_rn(fz);
        #define TRI(comp, ci)                                                   \
        {                                                                       \
            __half2 t0 = __hfma2(fx2, __hsub2(h2(r001.comp), h2(r000.comp)), h2(r000.comp)); \
            __half2 t1 = __hfma2(fx2, __hsub2(h2(r011.comp), h2(r010.comp)), h2(r010.comp)); \
            __half2 t2 = __hfma2(fx2, __hsub2(h2(r101.comp), h2(r100.comp)), h2(r100.comp)); \
            __half2 t3 = __hfma2(fx2, __hsub2(h2(r111.comp), h2(r110.comp)), h2(r110.comp)); \
            __half2 u0 = __hfma2(fy2, __hsub2(t1, t0), t0);                     \
            __half2 u1 = __hfma2(fy2, __hsub2(t3, t2), t2);                     \
            __half2 rr = __hfma2(fz2, __hsub2(u1, u0), u0);                     \
            float2 ff = __half22float2(rr);                                     \
            acc[2 * ci + 0] = __builtin_fmaf(mk, ff.x, acc[2 * ci + 0]);        \
            acc[2 * ci + 1] = __builtin_fmaf(mk, ff.y, acc[2 * ci + 1]);        \
        }
        TRI(x, 0) TRI(y, 1) TRI(z, 2) TRI(w, 3)
        #undef TRI
    }
}

// ========= K2: main — fused GN (A-tile once) + pure-VMEM point-split sampling =========
// Race-free softmax: 32 rows split disjointly across 4 waves, one writer per row.
__global__ void __launch_bounds__(256, 2) k_main(const unsigned short* __restrict__ xcb,
                                                 const float* __restrict__ partials,
                                                 const float* __restrict__ gn_w,
                                                 const float* __restrict__ gn_b,
                                                 const unsigned short* __restrict__ xpad,
                                                 const unsigned short* __restrict__ WcatB,
                                                 const float* __restrict__ bcat,
                                                 const unsigned short* __restrict__ outB,
                                                 const float* __restrict__ out_b,
                                                 float* __restrict__ out) {
    __shared__ float om_s[16 * OMS];             // 14592 B
    __shared__ unsigned short smb[16 * 72];      // 2304 B: A-tile, then S-tile
    __shared__ float pbuf[16 * 64];              // 4096 B: point-half-1 partials
    __shared__ float gnw_s[64], gnb_s[64], ws[8];
    int tid = threadIdx.x, wv = tid >> 6, lane = tid & 63;
    int quad = lane >> 4, col = lane & 15;
    // XCD swizzle over tiles: blocks sharing (blk&7) land on one XCD
    int sb = ((blockIdx.x & 7) << 8) | (blockIdx.x >> 3);
    // ---- phase 0: GN stats (1024 partial pairs) + gn params to LDS ----
    {
        if (tid < 64) { gnw_s[tid] = gn_w[tid]; gnb_s[tid] = gn_b[tid]; }
        float a = 0.f, b = 0.f;
#pragma unroll
        for (int i = 0; i < 2; ++i) {
            float4 t = *(const float4*)(partials + 4 * (tid + i * 256));
            a += t.x + t.z;
            b += t.y + t.w;
        }
#pragma unroll
        for (int off = 32; off > 0; off >>= 1) {
            a += __shfl_xor(a, off);
            b += __shfl_xor(b, off);
        }
        if (lane == 0) { ws[wv * 2] = a; ws[wv * 2 + 1] = b; }
    }
    __syncthreads();                             // #A
    const float Minv = 1.f / 2097152.f;
    float mu = (ws[0] + ws[2] + ws[4] + ws[6]) * Minv;
    float var = (ws[1] + ws[3] + ws[5] + ws[7]) * Minv - mu * mu;
    float rsq = rsqrtf(var + 1e-5f);
    // ---- phase 0c: A-tile (GN+GELU) built ONCE into smb (4 gathers/thread) ----
    {
        int v = tid >> 4, c0 = (tid & 15) * 4;
        int sv = vox_of(sb, v);
        u16x4 av;
#pragma unroll
        for (int i = 0; i < 4; ++i) {
            int c = c0 + i;
            float vx = (b2f1(xcb[(size_t)c * SP + sv]) - mu) * rsq * gnw_s[c] + gnb_s[c];
            float t2 = 1.5957691216057308f * (vx + 0.044715f * vx * vx * vx);
            av[i] = f2b(vx / (1.f + __expf(-t2)));
        }
        *(u16x4*)(&smb[v * 72 + c0]) = av;
    }
    __syncthreads();                             // #B: A-tile ready
    // ---- phase 1: offset+mask GEMM (16x64)@(64x224); A-fragments from LDS ----
    {
        bf16x8 a0 = *(const bf16x8*)(&smb[col * 72 + quad * 8]);
        bf16x8 a1 = *(const bf16x8*)(&smb[col * 72 + 32 + quad * 8]);
        for (int jt = wv; jt < 14; jt += 4) {
            int n0 = jt * 16;
            bf16x8 b0 = *(const bf16x8*)(WcatB + (n0 + col) * 64 + quad * 8);
            bf16x8 b1 = *(const bf16x8*)(WcatB + (n0 + col) * 64 + 32 + quad * 8);
            f32x4 c = {0.f, 0.f, 0.f, 0.f};
            c = __builtin_amdgcn_mfma_f32_16x16x32_bf16(a0, b0, c, 0, 0, 0);
            c = __builtin_amdgcn_mfma_f32_16x16x32_bf16(a1, b1, c, 0, 0, 0);
            float bb = bcat[n0 + col];
            // remap feature n -> padded 28-pt slot
            int n = n0 + col, slot;
            if (n < 162) slot = n + ((n >= 81) ? 3 : 0);
            else { int n2 = n - 162; slot = 168 + n2 + ((n2 >= 27) ? 1 : 0); }
            if (n < 216) {
#pragma unroll
                for (int r = 0; r < 4; ++r)
                    om_s[(quad * 4 + r) * OMS + slot] = c[r] + bb;
            }
        }
    }
    __syncthreads();                             // #C: om_s ready
    // ---- phase 2: softmax, 32 rows (16 vox x 2 grp), 8 rows/wave, ONE writer/row ----
    {
        int row = wv * 8 + (lane >> 3);          // 0..31, disjoint across waves
        int sub = lane & 7;                      // 8 lanes/row, 4 pts/lane
        int vloc = row >> 1, g = row & 1;
        float* m = &om_s[vloc * OMS + 168 + g * 28];
        float mv[4];
        float mx = -1e30f;
#pragma unroll
        for (int i = 0; i < 4; ++i) {
            int p = sub * 4 + i;
            mv[i] = (p < 27) ? m[p] : -1e30f;
            mx = fmaxf(mx, mv[i]);
        }
        mx = fmaxf(mx, __shfl_xor(mx, 1));
        mx = fmaxf(mx, __shfl_xor(mx, 2));
        mx = fmaxf(mx, __shfl_xor(mx, 4));
        float e[4], sm = 0.f;
#pragma unroll
        for (int i = 0; i < 4; ++i) { e[i] = __expf(mv[i] - mx); sm += e[i]; }
        sm += __shfl_xor(sm, 1);
        sm += __shfl_xor(sm, 2);
        sm += __shfl_xor(sm, 4);
        float inv = 1.f / sm;
#pragma unroll
        for (int i = 0; i < 4; ++i) {
            int p = sub * 4 + i;
            if (p < 27) m[p] = e[i] * inv;
        }
    }
    __syncthreads();                             // #C2: softmax visible to all waves
    // ---- phase 3: point-split VMEM sampling (waves 0-1: pts 0-13 | 2-3: pts 14-26) ----
    {
        int half = wv & 1, ph = wv >> 1;
        int v = half * 8 + (lane >> 3);          // local voxel 0..15
        int oct = lane & 7, gg = oct >> 2;       // channels oct*8..oct*8+7
        const float* orow = &om_s[v * OMS + gg * 84];
        const float* mrow = &om_s[v * OMS + 168 + gg * 28];
        int sv = vox_of(sb, v);
        float zb = (float)((sv >> 10) + 1);
        float yb = (float)(((sv >> 5) & 31) + 1);
        float xb = (float)((sv & 31) + 1);
        const char* volc = (const char*)xpad + oct * 16;
        float acc[8] = {0.f, 0.f, 0.f, 0.f, 0.f, 0.f, 0.f, 0.f};
        if (ph == 0) {
            sampleN<0, 14>(orow, mrow, volc, xb, yb, zb, acc);
        } else {
            sampleN<14, 13>(orow, mrow, volc, xb, yb, zb, acc);
            float* pp = &pbuf[v * 64 + oct * 8];
            *(f32x4*)(pp) = *(f32x4*)(acc);
            *(f32x4*)(pp + 4) = *(f32x4*)(acc + 4);
        }
        __syncthreads();                         // #D: pbuf ready (A-tile in smb now dead)
        if (ph == 0) {                           // combine halves + pack bf16
            const float* pp = &pbuf[v * 64 + oct * 8];
            bf16x8 sb8;
#pragma unroll
            for (int k = 0; k < 8; ++k) sb8[k] = (short)f2b(acc[k] + pp[k]);
            *(bf16x8*)(smb + v * 72 + oct * 8) = sb8;
        }
    }
    __syncthreads();                             // #E: smb (S-tile) ready
    // ---- phase 4: out projection (16x64)@(64x64); wave wv does col tile wv ----
    {
        bf16x8 oa0 = *(const bf16x8*)(smb + col * 72 + quad * 8);
        bf16x8 oa1 = *(const bf16x8*)(smb + col * 72 + 32 + quad * 8);
        int n0 = wv * 16;
        bf16x8 b0 = *(const bf16x8*)(outB + (n0 + col) * 64 + quad * 8);
        bf16x8 b1 = *(const bf16x8*)(outB + (n0 + col) * 64 + 32 + quad * 8);
        f32x4 c = {0.f, 0.f, 0.f, 0.f};
        c = __builtin_amdgcn_mfma_f32_16x16x32_bf16(oa0, b0, c, 0, 0, 0);
        c = __builtin_amdgcn_mfma_f32_16x16x32_bf16(oa1, b1, c, 0, 0, 0);
        float bb = out_b[n0 + col];
        int vr[4];
#pragma unroll
        for (int r = 0; r < 4; ++r) vr[r] = vox_of(sb, quad * 4 + r);
#pragma unroll
        for (int r = 0; r < 4; ++r)
            out[(size_t)vr[r] * 64 + n0 + col] = c[r] + bb;
    }
}

extern "C" void kernel_launch(void* const* d_in, const int* in_sizes, int n_in,
                              void* d_out, int out_size, void* d_ws, size_t ws_size,
                              hipStream_t stream) {
    const float* x      = (const float*)d_in[0];
    const float* dw_w   = (const float*)d_in[1];
    const float* gn_w   = (const float*)d_in[2];
    const float* gn_b   = (const float*)d_in[3];
    const float* inp_w  = (const float*)d_in[4];
    const float* inp_b  = (const float*)d_in[5];
    const float* off_w  = (const float*)d_in[6];
    const float* off_b  = (const float*)d_in[7];
    const float* mask_w = (const float*)d_in[8];
    const float* mask_b = (const float*)d_in[9];
    const float* out_w  = (const float*)d_in[10];
    const float* out_b  = (const float*)d_in[11];

    char* B = (char*)d_ws;
    float*          partials = (float*)(B + 256);                // 8 KB used
    unsigned short* xcb      = (unsigned short*)(B + 65792);     // 4 MB (bf16)
    unsigned short* xpad     = (unsigned short*)(B + 16843008);  // 7.02 MB (fp16)
    unsigned short* WcatB    = (unsigned short*)(B + 30890240);  // 28 KB
    float*          bcat     = (float*)(B + 30918912);           // 1 KB
    unsigned short* outB     = (unsigned short*)(B + 30928128);  // 8 KB
    float* out = (float*)d_out;

    k_front<<<72 + 1024 + 512 + 858, 256, 0, stream>>>(x, dw_w, off_w, mask_w, off_b, mask_b,
                                                       inp_w, inp_b, out_w, WcatB, bcat, outB,
                                                       xcb, partials, xpad);
    k_main<<<2048, 256, 0, stream>>>(xcb, partials, gn_w, gn_b, xpad,
                                     WcatB, bcat, outB, out_b, out);
}